// Round 8
// baseline (142.475 us; speedup 1.0000x reference)
//
#include <hip/hip_runtime.h>

// SimVQuantizer: B=8, D=128 (N_CB=8 x CDIM=16), H=W=32 -> 8192 pixels.
// Outputs (FLOAT32, concatenated flat):
//   quantized  [8,128,32,32]  = 1048576   @ 0
//   indices    [8,8,32,32]    =   65536   @ 1048576
//   commitment scalar         =       1   @ 1114112
//   new_codebooks [8,1024,16] =  131072   @ 1114113
//   new_count  [8,1024]       =    8192   @ 1245185
//   new_weight [8,1024,16]    =  131072   @ 1253377

#define NCB   8
#define VOCAB 1024
#define CDIM  16
#define NPIX  8192   // B*H*W
#define HW    1024   // H*W

#define OFF_QUANT  0
#define OFF_IDX    1048576
#define OFF_COMMIT 1114112
#define OFF_NCB    1114113
#define OFF_NCNT   1245185
#define OFF_NWT    1253377

// workspace (floats): commitment partials only (one per k_assign block).
// No memset: all 1024 words are written before k_statsupd reads them.
#define WS_CARR_OFF 0

typedef __attribute__((ext_vector_type(2))) float f32x2;

// numpy pairwise_sum (order-preserving 8-accumulator) for n=16:
// r[j] = a[j] + a[j+8];  res = ((r0+r1)+(r2+r3)) + ((r4+r5)+(r6+r7))
__device__ __forceinline__ float npsum16(const float m[16]) {
#pragma clang fp contract(off)
  float r0 = m[0] + m[8];
  float r1 = m[1] + m[9];
  float r2 = m[2] + m[10];
  float r3 = m[3] + m[11];
  float r4 = m[4] + m[12];
  float r5 = m[5] + m[13];
  float r6 = m[6] + m[14];
  float r7 = m[7] + m[15];
  return ((r0 + r1) + (r2 + r3)) + ((r4 + r5) + (r6 + r7));
}

__device__ __forceinline__ float npsum16sq(const float a[16]) {
#pragma clang fp contract(off)
  float m[16];
#pragma unroll
  for (int d = 0; d < 16; ++d) m[d] = a[d] * a[d];
  return npsum16(m);
}

// One entry's distance + argmin step, PACKED-PAIR form (VOP3P v_pk_*_f32).
// Exactly numpy's einsum contig tree, pairwise-decomposed:
//   m2_j = (m[2j], m[2j+1])           (8 pk_mul)
//   l01  = (m2_0+m2_2)+(m2_4+m2_6) = (l0, l1)
//   l23  = (m2_1+m2_3)+(m2_5+m2_7) = (l2, l3)   (6 pk_add)
//   dot  = (l01.x+l01.y) + (l23.x+l23.y) = (l0+l1)+(l2+l3)
// Every scalar IEEE op and its order is bit-identical to the scalar form.
__device__ __forceinline__ void proc_entry(const f32x2 zp[8], const f32x2 e2[8],
                                           float c2v, float z2, int idx,
                                           float& best, int& bi) {
#pragma clang fp contract(off)
  f32x2 m[8];
#pragma unroll
  for (int j = 0; j < 8; ++j) m[j] = zp[j] * e2[j];
  const f32x2 l01 = (m[0] + m[2]) + (m[4] + m[6]);
  const f32x2 l23 = (m[1] + m[3]) + (m[5] + m[7]);
  const float dot = (l01.x + l01.y) + (l23.x + l23.y);
  const float d2 = (z2 - 2.0f * dot) + c2v;
  const bool lt = d2 < best;  // strict: ascending scan -> first-wins
  best = lt ? d2 : best;
  bi = lt ? idx : bi;
}

// v9 k_assign: v8 shell (1024x512, scalar-stream entries, no atomics),
// inner loop re-expressed in packed float2 (VOP3P) — ~22 VALU instr/entry
// vs ~37 scalar, same bit-exact arithmetic. v8 control: 65us @ 62% VALUBusy
// with ~32us VALU floor -> issue-count-bound, so packing should cut dur.
__global__ __launch_bounds__(512, 4) void k_assign(
    const float* __restrict__ z, const float* __restrict__ cb,
    float* __restrict__ out, float* __restrict__ ws_commit_arr) {
  __shared__ float s_c2[VOCAB];    // 4KB
  __shared__ float s_best[8 * 64]; // 2KB
  __shared__ int s_bi[8 * 64];     // 2KB

  const int c = blockIdx.x >> 7;
  const int pchunk = blockIdx.x & 127;
  const int t = threadIdx.x;
  const int pix = t & 63;
  const int w = t >> 6;
  // provably wave-uniform wave id -> scalar (SGPR) entry addressing below
  const int wu = __builtin_amdgcn_readfirstlane(w);

  const float* cbc = cb + (size_t)c * VOCAB * CDIM;

  // ||cb||^2 for all 1024 entries (np.sum(cb*cb,-1), pairwise 8-acc order)
  for (int v = t; v < VOCAB; v += 512) {
    float e[16];
#pragma unroll
    for (int d = 0; d < 16; ++d) e[d] = cbc[(size_t)v * CDIM + d];
    s_c2[v] = npsum16sq(e);
  }

  const int n = pchunk * 64 + pix;  // pixel id in [0, 8192)
  const int b = n >> 10;            // batch
  const int hw = n & 1023;          // h*W + w

  // zp[n,c,d] = z[b, c*16+d, h, w]; 64-lane coalesced per d
  const float* zbase = z + ((size_t)(b * 128 + c * 16)) * HW + hw;
  float zv[16];
#pragma unroll
  for (int d = 0; d < 16; ++d) zv[d] = zbase[(size_t)d * HW];

  const float z2 = npsum16sq(zv);

  // natural-pair packing for the VOP3P loop
  f32x2 zp[8];
#pragma unroll
  for (int j = 0; j < 8; ++j) zp[j] = f32x2{zv[2 * j], zv[2 * j + 1]};

  __syncthreads();  // s_c2 ready

  // wave wu scans entries [wu*128, wu*128+128), ascending
  const int vbase = wu * 128;
  const f32x2* ep2 =
      reinterpret_cast<const f32x2*>(cbc + (size_t)vbase * CDIM);  // uniform

  float best = INFINITY;
  int bi = 0;

#pragma unroll 2
  for (int k = 0; k < 128; k += 2) {
    // two entries per body, uniform addresses -> scalar x16 loads
    f32x2 ea[8], eb[8];
#pragma unroll
    for (int j = 0; j < 8; ++j) ea[j] = ep2[(size_t)k * 8 + j];
#pragma unroll
    for (int j = 0; j < 8; ++j) eb[j] = ep2[(size_t)(k + 1) * 8 + j];
    const float cv0 = s_c2[vbase + k];
    const float cv1 = s_c2[vbase + k + 1];
    proc_entry(zp, ea, cv0, z2, vbase + k, best, bi);
    proc_entry(zp, eb, cv1, z2, vbase + k + 1, best, bi);
  }

  s_best[w * 64 + pix] = best;
  s_bi[w * 64 + pix] = bi;
  __syncthreads();

  // wave 0: combine the 8 per-wave candidates. Wave slices are disjoint
  // ascending ranges; break float ties by lower index -> np.argmin
  // first-wins exactly.
  if (t < 64) {
    best = s_best[t];
    bi = s_bi[t];
#pragma unroll
    for (int s = 1; s < 8; ++s) {
      const float ob = s_best[s * 64 + t];
      const int oi = s_bi[s * 64 + t];
      const bool take = (ob < best) || (ob == best && oi < bi);
      best = take ? ob : best;
      bi = take ? oi : bi;
    }

    // t<64 => wave 0, pix == t: zv holds THIS pixel's z (bit-identical)
    const float* qe = cbc + (size_t)bi * CDIM;  // winning entry (L2-hot)
    float comm = 0.f;
#pragma unroll
    for (int d = 0; d < 16; ++d) {
      float zq = qe[d];
      float diff, qst;
      {
#pragma clang fp contract(off)
        diff = zv[d] - zq;
        qst = zv[d] + (zq - zv[d]);  // zq_st = zp + (zq - zp), as np computes
      }
      comm += diff * diff;
      out[OFF_QUANT + ((size_t)(b * 128 + c * 16 + d)) * HW + hw] = qst;
    }
    out[OFF_IDX + ((size_t)(b * NCB + c)) * HW + hw] = (float)bi;

    // commitment partial: ONE plain store per block (no atomics)
#pragma unroll
    for (int off = 32; off; off >>= 1) comm += __shfl_down(comm, off);
    if (t == 0) ws_commit_arr[blockIdx.x] = comm;
  }
}

// k_statsupd v9: 128 blocks = (c, d) x 1024 threads; fuses v8's k_stats +
// k_update (one fewer boundary, no stats workspace). EVERY block builds the
// full count histogram for its c (counts are exact integers -> identical
// across the 16 d-blocks; LDS atomics are cheap), so each block computes
// nsum independently and writes its own output slice. All loads hoisted
// (16 regs — the v7 spill lesson), 128 blocks spread across CUs.
__global__ __launch_bounds__(1024, 2) void k_statsupd(
    const float* __restrict__ z, const float* __restrict__ outbuf,
    const float* __restrict__ ema_count, const float* __restrict__ ema_weight,
    const float* __restrict__ ws_commit_arr, float* __restrict__ out) {
  __shared__ float s_sum[VOCAB];  // 4KB
  __shared__ float s_cnt[VOCAB];  // 4KB
  __shared__ float s_fred[16];
  __shared__ float s_n;
  __shared__ double s_dred[16];

  const int c = blockIdx.x >> 4;
  const int d = blockIdx.x & 15;
  const int t = threadIdx.x;
  const int lane = t & 63;
  const int wv = t >> 6;

  s_sum[t] = 0.f;
  s_cnt[t] = 0.f;

  // hoist all loads: 8 idx + 8 z, independent -> one latency exposure
  int bidx[8];
  float zval[8];
#pragma unroll
  for (int k = 0; k < 8; ++k) {
    bidx[k] = (int)outbuf[OFF_IDX + ((size_t)(k * NCB + c)) * HW + t];
    zval[k] = z[((size_t)(k * 128 + c * 16 + d)) * HW + t];
  }
  __syncthreads();  // zero-init visible

#pragma unroll
  for (int k = 0; k < 8; ++k) {
    atomicAdd(&s_cnt[bidx[k]], 1.0f);    // ds_add_f32, banked
    atomicAdd(&s_sum[bidx[k]], zval[k]);
  }
  __syncthreads();

  // new_count (d==0 block only) + per-block nsum
  const float ncv = 0.99f * ema_count[c * VOCAB + t] + 0.01f * s_cnt[t];
  if (d == 0) out[OFF_NCNT + c * VOCAB + t] = ncv;
  float psum = ncv;
#pragma unroll
  for (int off = 32; off; off >>= 1) psum += __shfl_down(psum, off);
  if (lane == 0) s_fred[wv] = psum;
  __syncthreads();
  if (t == 0) {
    float s = 0.f;
#pragma unroll
    for (int i = 0; i < 16; ++i) s += s_fred[i];
    s_n = s;
  }
  __syncthreads();
  const float nsum = s_n;
  const float veps = 0.01024f;  // VOCAB * 1e-5

  // new_weight / new_codebooks slice for (c, d): element v = t
  const float cnt = (ncv + 1e-5f) / (nsum + veps) * nsum;
  const size_t gi = (size_t)c * VOCAB * CDIM + (size_t)t * CDIM + d;
  const float nw = 0.99f * ema_weight[gi] + 0.01f * s_sum[t];
  out[OFF_NWT + gi] = nw;
  out[OFF_NCB + gi] = nw / cnt;

  // commitment: block 0 reduces the 1024 f32 partials in f64
  if (blockIdx.x == 0) {
    double ps = (double)ws_commit_arr[t];
#pragma unroll
    for (int off = 32; off; off >>= 1) ps += __shfl_down(ps, off);
    if (lane == 0) s_dred[wv] = ps;
    __syncthreads();
    if (t == 0) {
      double sd = 0.0;
#pragma unroll
      for (int i = 0; i < 16; ++i) sd += s_dred[i];
      out[OFF_COMMIT] = (float)(sd / 1048576.0);
    }
  }
}

extern "C" void kernel_launch(void* const* d_in, const int* in_sizes, int n_in,
                              void* d_out, int out_size, void* d_ws,
                              size_t ws_size, hipStream_t stream) {
  const float* z = (const float*)d_in[0];
  const float* codebooks = (const float*)d_in[1];
  const float* ema_count = (const float*)d_in[2];
  const float* ema_weight = (const float*)d_in[3];
  float* out = (float*)d_out;

  float* ws_commit_arr = (float*)d_ws + WS_CARR_OFF;

  // no memset: commit_arr fully written by k_assign; histograms are in LDS

  k_assign<<<dim3(1024), dim3(512), 0, stream>>>(z, codebooks, out,
                                                 ws_commit_arr);
  k_statsupd<<<dim3(128), dim3(1024), 0, stream>>>(z, out, ema_count,
                                                   ema_weight, ws_commit_arr,
                                                   out);
}